// Round 3
// baseline (435.952 us; speedup 1.0000x reference)
//
#include <hip/hip_runtime.h>
#include <stdint.h>

#define B_ 8
#define C_ 256
#define N_ 2048
#define HC 128

typedef float f32x4 __attribute__((ext_vector_type(4)));
typedef short s16x8 __attribute__((ext_vector_type(8)));

__device__ __forceinline__ unsigned short f2bf(float f){
  union { float f; unsigned u; } v; v.f = f;
  unsigned r = v.u + 0x7FFF + ((v.u >> 16) & 1u);
  return (unsigned short)(r >> 16);
}

// ---------------- prep: weights -> bf16, BN affine fold ----------------
struct PrepArgs {
  const float *s0,*s1,*s2,*s3,*s4,*s5;
  unsigned short *d0,*d1,*d2,*d3,*d4,*d5;
  const float *b1,*g1,*be1,*m1,*v1;
  const float *b2,*g2,*be2,*m2,*v2;
  float *sc1,*sh1,*sc2,*sh2;
};

__global__ __launch_bounds__(256) void k_prep(PrepArgs a){
  int gid = blockIdx.x*256 + threadIdx.x;
  const int S0=65536, S1=131072, S2=196608, S3=229376, S4=245760, S5=278528;
  if (gid < S0)      a.d0[gid]    = f2bf(a.s0[gid]);
  else if (gid < S1) a.d1[gid-S0] = f2bf(a.s1[gid-S0]);
  else if (gid < S2) a.d2[gid-S1] = f2bf(a.s2[gid-S1]);
  else if (gid < S3) a.d3[gid-S2] = f2bf(a.s3[gid-S2]);
  else if (gid < S4) a.d4[gid-S3] = f2bf(a.s4[gid-S3]);
  else if (gid < S5) a.d5[gid-S4] = f2bf(a.s5[gid-S4]);
  else if (gid < S5+128){
    int o = gid - S5;
    float inv = a.g1[o] * rsqrtf(a.v1[o] + 1e-5f);
    a.sc1[o] = inv;
    a.sh1[o] = a.b1[o]*inv + a.be1[o] - a.m1[o]*inv;
  } else if (gid < S5+256){
    int o = gid - S5 - 128;
    float inv = a.g2[o] * rsqrtf(a.v2[o] + 1e-5f);
    a.sc2[o] = inv;
    a.sh2[o] = a.b2[o]*inv + a.be2[o] - a.m2[o]*inv;
  }
}

// ---------------- x [B][C][N] f32 -> xn [B][N][C] bf16 ----------------
__global__ __launch_bounds__(256) void k_transpose_x(const float* __restrict__ x,
                                                     unsigned short* __restrict__ xn){
  __shared__ float lds[64][65];
  int b = blockIdx.z, ct = blockIdx.y, nt = blockIdx.x;
  int n0 = nt*64, c0 = ct*64;
  const float* xb = x + (size_t)b*C_*N_;
  int tn = threadIdx.x & 63, tc0 = threadIdx.x >> 6;
  #pragma unroll
  for (int cc = tc0; cc < 64; cc += 4)
    lds[tn][cc] = xb[(size_t)(c0+cc)*N_ + n0 + tn];
  __syncthreads();
  unsigned short* xnb = xn + (size_t)b*N_*C_;
  int cl = threadIdx.x & 63, nl0 = threadIdx.x >> 6;
  #pragma unroll
  for (int nl = nl0; nl < 64; nl += 4)
    xnb[(size_t)(n0+nl)*C_ + c0 + cl] = f2bf(lds[nl][cl]);
}

// ---------------- QKV GEMM: xn @ W^T + b ----------------
__global__ __launch_bounds__(256) void k_qkv(
    const unsigned short* __restrict__ xn,
    const unsigned short* __restrict__ wqb, const unsigned short* __restrict__ wkb,
    const unsigned short* __restrict__ wvb,
    const float* __restrict__ bq, const float* __restrict__ bk, const float* __restrict__ bv,
    unsigned short* __restrict__ Qn, unsigned short* __restrict__ Kn,
    unsigned short* __restrict__ Vc)
{
  __shared__ unsigned short Alds[64][256];
  __shared__ unsigned short Tlds[64][260];
  int b = blockIdx.y, nt = blockIdx.x, z = blockIdx.z;
  int nb = nt*64;
  const unsigned short* W = (z==0) ? wqb : (z==1 ? wkb : wvb);
  const float* bias = (z==0) ? bq : (z==1 ? bk : bv);
  const unsigned short* Ab = xn + ((size_t)b*N_ + nb)*C_;
  for (int i = threadIdx.x; i < 64*32; i += 256){
    int r = i >> 5, cv = i & 31;
    *(s16x8*)&Alds[r][(cv*8) ^ ((r&7)<<3)] = *(const s16x8*)&Ab[(size_t)r*C_ + cv*8];
  }
  __syncthreads();
  int w = threadIdx.x >> 6, l = threadIdx.x & 63, lr = l & 15, lq = l >> 4;
  f32x4 acc[16];
  f32x4 zero = {0.f,0.f,0.f,0.f};
  #pragma unroll
  for (int i=0;i<16;i++) acc[i] = zero;
  #pragma unroll
  for (int ks = 0; ks < 8; ks++){
    s16x8 a = *(const s16x8*)&Alds[16*w + lr][(32*ks + 8*lq) ^ ((lr&7)<<3)];
    #pragma unroll
    for (int ct = 0; ct < 16; ct++){
      s16x8 bw = *(const s16x8*)&W[(size_t)(16*ct + lr)*C_ + 32*ks + 8*lq];
      acc[ct] = __builtin_amdgcn_mfma_f32_16x16x32_bf16(a, bw, acc[ct], 0, 0, 0);
    }
  }
  if (z < 2){
    unsigned short* ob = (z==0 ? Qn : Kn) + ((size_t)b*N_ + nb)*C_;
    #pragma unroll
    for (int ct = 0; ct < 16; ct++){
      int o = 16*ct + lr;
      float bi = bias[o];
      #pragma unroll
      for (int r = 0; r < 4; r++){
        int row = 16*w + 4*lq + r;
        ob[(size_t)row*C_ + o] = f2bf(acc[ct][r] + bi);
      }
    }
  } else {
    #pragma unroll
    for (int ct = 0; ct < 16; ct++){
      int o = 16*ct + lr;
      float bi = bias[o];
      #pragma unroll
      for (int r = 0; r < 4; r++)
        Tlds[16*w + 4*lq + r][o] = f2bf(acc[ct][r] + bi);
    }
    __syncthreads();
    unsigned short* vb = Vc + (size_t)b*C_*N_;
    int j = threadIdx.x & 63, o0 = threadIdx.x >> 6;
    #pragma unroll
    for (int o = o0; o < 256; o += 4)
      vb[(size_t)o*N_ + nb + j] = Tlds[j][o];
  }
}

// ---------------- attention: barrier-free, no-max flash, m-split ----------------
// grid (32 nt, 8 b, 2 mh), 256 thr. Each wave independent on 16 q-rows, 16 m-tiles.
// P = exp(S*beta) raw (f32-safe: |logit| <~ 60), O and row-sum unnormalized ->
// partials merged by k_merge. K/V B-frags direct from L2; only per-wave Plds.
__global__ __launch_bounds__(256) void k_attn(
    const unsigned short* __restrict__ Qn, const unsigned short* __restrict__ Kn,
    const unsigned short* __restrict__ Vc, const float* __restrict__ beta,
    float* __restrict__ Op, float* __restrict__ Ls)
{
  __shared__ unsigned short Plds[4][16][64];
  int b = blockIdx.y, nt = blockIdx.x, mh = blockIdx.z;
  int nb = nt*64;
  const unsigned short* Qb = Qn + (size_t)b*N_*C_;
  const unsigned short* Kb = Kn + (size_t)b*N_*C_;
  const unsigned short* Vb = Vc + (size_t)b*C_*N_;
  const float* betab = beta + (size_t)b*N_*N_;
  int w = threadIdx.x >> 6, l = threadIdx.x & 63, lr = l & 15, lq = l >> 4;
  const int mt0 = mh*16;

  // Q fragments (regs, whole kernel)
  s16x8 qf[8];
  {
    const unsigned short* qrow = Qb + (size_t)(nb + 16*w + lr)*C_;
    #pragma unroll
    for (int ks = 0; ks < 8; ks++)
      qf[ks] = *(const s16x8*)&qrow[32*ks + 8*lq];
  }
  f32x4 zero = {0.f,0.f,0.f,0.f};
  f32x4 oacc[16];
  #pragma unroll
  for (int i=0;i<16;i++) oacc[i] = zero;
  float psum[4] = {0.f,0.f,0.f,0.f};

  float bA[16], bB[16];
  #pragma unroll
  for (int t4=0;t4<4;t4++)
    #pragma unroll
    for (int r=0;r<4;r++)
      bA[4*t4+r] = betab[(size_t)(nb + 16*w + 4*lq + r)*N_ + mt0*64 + 16*t4 + lr];

#define ATTN_TILE(T, BCUR, BNEXT)                                              \
  {                                                                            \
    const int mb_ = (T)*64;                                                    \
    const int tn_ = ((T)+1 < mt0+16) ? (T)+1 : mt0;                            \
    /* prefetch next beta tile into regs */                                    \
    _Pragma("unroll")                                                          \
    for (int t4=0;t4<4;t4++)                                                   \
      _Pragma("unroll")                                                        \
      for (int r=0;r<4;r++)                                                    \
        BNEXT[4*t4+r] =                                                        \
          betab[(size_t)(nb + 16*w + 4*lq + r)*N_ + tn_*64 + 16*t4 + lr];      \
    /* S = Q K^T, K B-frags direct from L2 */                                  \
    f32x4 s_[4];                                                               \
    _Pragma("unroll")                                                          \
    for (int t4=0;t4<4;t4++) s_[t4] = zero;                                    \
    _Pragma("unroll")                                                          \
    for (int t4=0;t4<4;t4++){                                                  \
      s16x8 kf_[8];                                                            \
      _Pragma("unroll")                                                        \
      for (int ks=0;ks<8;ks++)                                                 \
        kf_[ks] = *(const s16x8*)                                              \
            &Kb[(size_t)(mb_ + 16*t4 + lr)*C_ + 32*ks + 8*lq];                 \
      _Pragma("unroll")                                                        \
      for (int ks=0;ks<8;ks++)                                                 \
        s_[t4] = __builtin_amdgcn_mfma_f32_16x16x32_bf16(qf[ks], kf_[ks],      \
                                                         s_[t4], 0, 0, 0);     \
    }                                                                          \
    /* P = exp(S*beta); accumulate per-lane row-sums; pack to Plds */          \
    _Pragma("unroll")                                                          \
    for (int t4=0;t4<4;t4++)                                                   \
      _Pragma("unroll")                                                        \
      for (int r=0;r<4;r++){                                                   \
        float p_ = __expf(s_[t4][r] * BCUR[4*t4+r]);                           \
        psum[r] += p_;                                                         \
        int i_ = 4*lq + r;                                                     \
        Plds[w][i_][(16*t4 + lr) ^ ((i_&7)<<3)] = f2bf(p_);                    \
      }                                                                        \
    /* PV: O += P * V, V B-frags direct from L2 */                             \
    _Pragma("unroll")                                                          \
    for (int kk=0; kk<2; kk++){                                                \
      s16x8 ap_ = *(const s16x8*)&Plds[w][lr][(32*kk + 8*lq) ^ ((lr&7)<<3)];   \
      _Pragma("unroll")                                                        \
      for (int ct=0; ct<16; ct++){                                             \
        s16x8 bv_ = *(const s16x8*)                                            \
            &Vb[(size_t)(16*ct + lr)*N_ + mb_ + 32*kk + 8*lq];                 \
        oacc[ct] = __builtin_amdgcn_mfma_f32_16x16x32_bf16(ap_, bv_,           \
                                                           oacc[ct], 0,0,0);   \
      }                                                                        \
    }                                                                          \
  }

  for (int tt = mt0; tt < mt0+16; tt += 2){
    ATTN_TILE(tt,   bA, bB)
    ATTN_TILE(tt+1, bB, bA)
  }
#undef ATTN_TILE

  // reduce row-sums across the 16-lane lr group (lanes share lq -> same rows)
  #pragma unroll
  for (int r=0;r<4;r++){
    #pragma unroll
    for (int d=1; d<16; d<<=1) psum[r] += __shfl_xor(psum[r], d, 64);
  }
  // store partials
  float* Ob = Op + ((size_t)mh*8 + b)*(size_t)N_*C_;
  #pragma unroll
  for (int ct=0; ct<16; ct++)
    #pragma unroll
    for (int r=0;r<4;r++)
      Ob[(size_t)(nb + 16*w + 4*lq + r)*C_ + 16*ct + lr] = oacc[ct][r];
  if (lr == 0){
    float* Lb = Ls + ((size_t)mh*8 + b)*N_;
    #pragma unroll
    for (int r=0;r<4;r++) Lb[nb + 16*w + 4*lq + r] = psum[r];
  }
}

// ---------------- merge the two m-halves, normalize, -> Mn bf16 ----------------
__global__ __launch_bounds__(256) void k_merge(
    const float* __restrict__ Op, const float* __restrict__ Ls,
    unsigned short* __restrict__ Mn)
{
  int gid = blockIdx.x*256 + threadIdx.x;          // 8*2048*64 f32x4 chunks
  int c4 = gid & 63, n = (gid >> 6) & 2047, b = gid >> 17;
  size_t i0 = ((size_t)b*N_ + n)*C_ + c4*4;
  f32x4 o0 = *(const f32x4*)&Op[i0];
  f32x4 o1 = *(const f32x4*)&Op[(size_t)8*N_*C_ + i0];
  float inv = 1.f / (Ls[(size_t)b*N_ + n] + Ls[(size_t)8*N_ + (size_t)b*N_ + n]);
  unsigned short* m = Mn + i0;
  #pragma unroll
  for (int j=0;j<4;j++) m[j] = f2bf((o0[j] + o1[j]) * inv);
}

// ---------------- generic NT GEMM: out[n][o] = epi(sum_c A[n][c] W[o][c]) ----------------
template<int CIN, int COUT, int MODE>
__global__ __launch_bounds__(256) void k_gemm(
    const unsigned short* __restrict__ A, const unsigned short* __restrict__ W,
    const float* __restrict__ bias, const float* __restrict__ sc,
    const float* __restrict__ sh, unsigned short* __restrict__ out)
{
  __shared__ unsigned short Alds[64][CIN];
  int b = blockIdx.y, nt = blockIdx.x, nb = nt*64;
  const unsigned short* Ab = A + ((size_t)b*N_ + nb)*CIN;
  constexpr int PR = CIN/8;
  for (int i = threadIdx.x; i < 64*PR; i += 256){
    int r = i / PR, cv = i % PR;
    *(s16x8*)&Alds[r][(cv*8) ^ ((r&7)<<3)] = *(const s16x8*)&Ab[(size_t)r*CIN + cv*8];
  }
  __syncthreads();
  int w = threadIdx.x >> 6, l = threadIdx.x & 63, lr = l & 15, lq = l >> 4;
  constexpr int NT = COUT/16;
  f32x4 acc[NT];
  f32x4 zero = {0.f,0.f,0.f,0.f};
  #pragma unroll
  for (int i=0;i<NT;i++) acc[i] = zero;
  #pragma unroll
  for (int ks = 0; ks < CIN/32; ks++){
    s16x8 a = *(const s16x8*)&Alds[16*w + lr][(32*ks + 8*lq) ^ ((lr&7)<<3)];
    #pragma unroll
    for (int ct = 0; ct < NT; ct++){
      s16x8 bw = *(const s16x8*)&W[(size_t)(16*ct + lr)*CIN + 32*ks + 8*lq];
      acc[ct] = __builtin_amdgcn_mfma_f32_16x16x32_bf16(a, bw, acc[ct], 0, 0, 0);
    }
  }
  unsigned short* ob = out + ((size_t)b*N_ + nb)*COUT;
  #pragma unroll
  for (int ct = 0; ct < NT; ct++){
    int o = 16*ct + lr;
    float bi = (MODE==0) ? bias[o] : 0.f;
    float s_ = (MODE==1) ? sc[o] : 0.f;
    float h_ = (MODE==1) ? sh[o] : 0.f;
    #pragma unroll
    for (int r = 0; r < 4; r++){
      int row = 16*w + 4*lq + r;
      float y;
      if (MODE==1) y = fmaxf(acc[ct][r]*s_ + h_, 0.f);
      else         y = acc[ct][r] + bi;
      ob[(size_t)row*COUT + o] = f2bf(y);
    }
  }
}

// ---------------- final: out[b][o][n] = x + h2n @ w3^T + b3 ----------------
__global__ __launch_bounds__(256) void k_mlp3(
    const unsigned short* __restrict__ A, const unsigned short* __restrict__ W,
    const float* __restrict__ b3, const float* __restrict__ x,
    float* __restrict__ out)
{
  __shared__ unsigned short Alds[64][128];
  __shared__ float Dlds[64][257];
  int b = blockIdx.y, nt = blockIdx.x, nb = nt*64;
  const unsigned short* Ab = A + ((size_t)b*N_ + nb)*HC;
  for (int i = threadIdx.x; i < 64*16; i += 256){
    int r = i >> 4, cv = i & 15;
    *(s16x8*)&Alds[r][(cv*8) ^ ((r&7)<<3)] = *(const s16x8*)&Ab[(size_t)r*HC + cv*8];
  }
  __syncthreads();
  int w = threadIdx.x >> 6, l = threadIdx.x & 63, lr = l & 15, lq = l >> 4;
  f32x4 acc[16];
  f32x4 zero = {0.f,0.f,0.f,0.f};
  #pragma unroll
  for (int i=0;i<16;i++) acc[i] = zero;
  #pragma unroll
  for (int ks = 0; ks < 4; ks++){
    s16x8 a = *(const s16x8*)&Alds[16*w + lr][(32*ks + 8*lq) ^ ((lr&7)<<3)];
    #pragma unroll
    for (int ct = 0; ct < 16; ct++){
      s16x8 bw = *(const s16x8*)&W[(size_t)(16*ct + lr)*HC + 32*ks + 8*lq];
      acc[ct] = __builtin_amdgcn_mfma_f32_16x16x32_bf16(a, bw, acc[ct], 0, 0, 0);
    }
  }
  #pragma unroll
  for (int ct = 0; ct < 16; ct++){
    int o = 16*ct + lr;
    float bi = b3[o];
    #pragma unroll
    for (int r = 0; r < 4; r++)
      Dlds[16*w + 4*lq + r][o] = acc[ct][r] + bi;
  }
  __syncthreads();
  const float* xb = x + (size_t)b*C_*N_;
  float* ob = out + (size_t)b*C_*N_;
  int j = threadIdx.x & 63, o0 = threadIdx.x >> 6;
  #pragma unroll
  for (int o = o0; o < 256; o += 4)
    ob[(size_t)o*N_ + nb + j] = xb[(size_t)o*N_ + nb + j] + Dlds[j][o];
}

extern "C" void kernel_launch(void* const* d_in, const int* in_sizes, int n_in,
                              void* d_out, int out_size, void* d_ws, size_t ws_size,
                              hipStream_t stream)
{
  const float* x    = (const float*)d_in[0];
  const float* beta = (const float*)d_in[1];
  const float* wq = (const float*)d_in[2];  const float* bq = (const float*)d_in[3];
  const float* wk = (const float*)d_in[4];  const float* bk = (const float*)d_in[5];
  const float* wv = (const float*)d_in[6];  const float* bv = (const float*)d_in[7];
  const float* w1 = (const float*)d_in[8];  const float* b1 = (const float*)d_in[9];
  const float* g1 = (const float*)d_in[10]; const float* be1= (const float*)d_in[11];
  const float* m1 = (const float*)d_in[12]; const float* v1 = (const float*)d_in[13];
  const float* w2 = (const float*)d_in[14]; const float* b2 = (const float*)d_in[15];
  const float* g2 = (const float*)d_in[16]; const float* be2= (const float*)d_in[17];
  const float* m2 = (const float*)d_in[18]; const float* v2 = (const float*)d_in[19];
  const float* w3 = (const float*)d_in[20]; const float* b3 = (const float*)d_in[21];

  char* p = (char*)d_ws;
  auto alloc = [&](size_t n){ char* r = p; p += (n + 255) & ~(size_t)255; return r; };
  unsigned short* xn  = (unsigned short*)alloc((size_t)B_*N_*C_*2);
  unsigned short* Qn  = (unsigned short*)alloc((size_t)B_*N_*C_*2);
  unsigned short* Kn  = (unsigned short*)alloc((size_t)B_*N_*C_*2);
  unsigned short* Vc  = (unsigned short*)alloc((size_t)B_*N_*C_*2);
  unsigned short* Mn  = (unsigned short*)alloc((size_t)B_*N_*C_*2);
  unsigned short* h1n = (unsigned short*)alloc((size_t)B_*N_*HC*2);
  unsigned short* h2n = (unsigned short*)alloc((size_t)B_*N_*HC*2);
  float* Op = (float*)alloc((size_t)2*B_*N_*C_*4);
  float* Ls = (float*)alloc((size_t)2*B_*N_*4);
  unsigned short* wqb = (unsigned short*)alloc(65536*2);
  unsigned short* wkb = (unsigned short*)alloc(65536*2);
  unsigned short* wvb = (unsigned short*)alloc(65536*2);
  unsigned short* w1b = (unsigned short*)alloc(32768*2);
  unsigned short* w2b = (unsigned short*)alloc(16384*2);
  unsigned short* w3b = (unsigned short*)alloc(32768*2);
  float* sc1 = (float*)alloc(128*4);
  float* sh1 = (float*)alloc(128*4);
  float* sc2 = (float*)alloc(128*4);
  float* sh2 = (float*)alloc(128*4);

  PrepArgs pa;
  pa.s0 = wq; pa.s1 = wk; pa.s2 = wv; pa.s3 = w1; pa.s4 = w2; pa.s5 = w3;
  pa.d0 = wqb; pa.d1 = wkb; pa.d2 = wvb; pa.d3 = w1b; pa.d4 = w2b; pa.d5 = w3b;
  pa.b1 = b1; pa.g1 = g1; pa.be1 = be1; pa.m1 = m1; pa.v1 = v1;
  pa.b2 = b2; pa.g2 = g2; pa.be2 = be2; pa.m2 = m2; pa.v2 = v2;
  pa.sc1 = sc1; pa.sh1 = sh1; pa.sc2 = sc2; pa.sh2 = sh2;

  k_prep<<<dim3(1089), dim3(256), 0, stream>>>(pa);
  k_transpose_x<<<dim3(32, 4, 8), dim3(256), 0, stream>>>(x, xn);
  k_qkv<<<dim3(32, 8, 3), dim3(256), 0, stream>>>(xn, wqb, wkb, wvb, bq, bk, bv, Qn, Kn, Vc);
  k_attn<<<dim3(32, 8, 2), dim3(256), 0, stream>>>(Qn, Kn, Vc, beta, Op, Ls);
  k_merge<<<dim3(4096), dim3(256), 0, stream>>>(Op, Ls, Mn);
  k_gemm<256,128,1><<<dim3(32, 8), dim3(256), 0, stream>>>(Mn, w1b, b1, sc1, sh1, h1n);
  k_gemm<128,128,1><<<dim3(32, 8), dim3(256), 0, stream>>>(h1n, w2b, b2, sc2, sh2, h2n);
  k_mlp3<<<dim3(32, 8), dim3(256), 0, stream>>>(h2n, w3b, b3, x, (float*)d_out);
}

// Round 4
// 202.926 us; speedup vs baseline: 2.1483x; 2.1483x over previous
//
#include <hip/hip_runtime.h>
#include <stdint.h>

#define B_ 8
#define C_ 256
#define N_ 2048
#define HC 128

typedef float f32x4 __attribute__((ext_vector_type(4)));
typedef short s16x8 __attribute__((ext_vector_type(8)));

__device__ __forceinline__ unsigned short f2bf(float f){
  union { float f; unsigned u; } v; v.f = f;
  unsigned r = v.u + 0x7FFF + ((v.u >> 16) & 1u);
  return (unsigned short)(r >> 16);
}

// ---------------- prep: weights -> bf16, BN affine fold ----------------
struct PrepArgs {
  const float *s0,*s1,*s2,*s3,*s4,*s5;
  unsigned short *d0,*d1,*d2,*d3,*d4,*d5;
  const float *b1,*g1,*be1,*m1,*v1;
  const float *b2,*g2,*be2,*m2,*v2;
  float *sc1,*sh1,*sc2,*sh2;
};

__global__ __launch_bounds__(256) void k_prep(PrepArgs a){
  int gid = blockIdx.x*256 + threadIdx.x;
  const int S0=65536, S1=131072, S2=196608, S3=229376, S4=245760, S5=278528;
  if (gid < S0)      a.d0[gid]    = f2bf(a.s0[gid]);
  else if (gid < S1) a.d1[gid-S0] = f2bf(a.s1[gid-S0]);
  else if (gid < S2) a.d2[gid-S1] = f2bf(a.s2[gid-S1]);
  else if (gid < S3) a.d3[gid-S2] = f2bf(a.s3[gid-S2]);
  else if (gid < S4) a.d4[gid-S3] = f2bf(a.s4[gid-S3]);
  else if (gid < S5) a.d5[gid-S4] = f2bf(a.s5[gid-S4]);
  else if (gid < S5+128){
    int o = gid - S5;
    float inv = a.g1[o] * rsqrtf(a.v1[o] + 1e-5f);
    a.sc1[o] = inv;
    a.sh1[o] = a.b1[o]*inv + a.be1[o] - a.m1[o]*inv;
  } else if (gid < S5+256){
    int o = gid - S5 - 128;
    float inv = a.g2[o] * rsqrtf(a.v2[o] + 1e-5f);
    a.sc2[o] = inv;
    a.sh2[o] = a.b2[o]*inv + a.be2[o] - a.m2[o]*inv;
  }
}

// ---------------- x [B][C][N] f32 -> xn [B][N][C] bf16 ----------------
__global__ __launch_bounds__(256) void k_transpose_x(const float* __restrict__ x,
                                                     unsigned short* __restrict__ xn){
  __shared__ float lds[64][65];
  int b = blockIdx.z, ct = blockIdx.y, nt = blockIdx.x;
  int n0 = nt*64, c0 = ct*64;
  const float* xb = x + (size_t)b*C_*N_;
  int tn = threadIdx.x & 63, tc0 = threadIdx.x >> 6;
  #pragma unroll
  for (int cc = tc0; cc < 64; cc += 4)
    lds[tn][cc] = xb[(size_t)(c0+cc)*N_ + n0 + tn];
  __syncthreads();
  unsigned short* xnb = xn + (size_t)b*N_*C_;
  int cl = threadIdx.x & 63, nl0 = threadIdx.x >> 6;
  #pragma unroll
  for (int nl = nl0; nl < 64; nl += 4)
    xnb[(size_t)(n0+nl)*C_ + c0 + cl] = f2bf(lds[nl][cl]);
}

// ---------------- QKV GEMM: xn @ W^T + b ----------------
__global__ __launch_bounds__(256) void k_qkv(
    const unsigned short* __restrict__ xn,
    const unsigned short* __restrict__ wqb, const unsigned short* __restrict__ wkb,
    const unsigned short* __restrict__ wvb,
    const float* __restrict__ bq, const float* __restrict__ bk, const float* __restrict__ bv,
    unsigned short* __restrict__ Qn, unsigned short* __restrict__ Kn,
    unsigned short* __restrict__ Vc)
{
  __shared__ unsigned short Alds[64][256];
  __shared__ unsigned short Tlds[64][260];
  int b = blockIdx.y, nt = blockIdx.x, z = blockIdx.z;
  int nb = nt*64;
  const unsigned short* W = (z==0) ? wqb : (z==1 ? wkb : wvb);
  const float* bias = (z==0) ? bq : (z==1 ? bk : bv);
  const unsigned short* Ab = xn + ((size_t)b*N_ + nb)*C_;
  for (int i = threadIdx.x; i < 64*32; i += 256){
    int r = i >> 5, cv = i & 31;
    *(s16x8*)&Alds[r][(cv*8) ^ ((r&7)<<3)] = *(const s16x8*)&Ab[(size_t)r*C_ + cv*8];
  }
  __syncthreads();
  int w = threadIdx.x >> 6, l = threadIdx.x & 63, lr = l & 15, lq = l >> 4;
  f32x4 acc[16];
  f32x4 zero = {0.f,0.f,0.f,0.f};
  #pragma unroll
  for (int i=0;i<16;i++) acc[i] = zero;
  #pragma unroll
  for (int ks = 0; ks < 8; ks++){
    s16x8 a = *(const s16x8*)&Alds[16*w + lr][(32*ks + 8*lq) ^ ((lr&7)<<3)];
    #pragma unroll
    for (int ct = 0; ct < 16; ct++){
      s16x8 bw = *(const s16x8*)&W[(size_t)(16*ct + lr)*C_ + 32*ks + 8*lq];
      acc[ct] = __builtin_amdgcn_mfma_f32_16x16x32_bf16(a, bw, acc[ct], 0, 0, 0);
    }
  }
  if (z < 2){
    unsigned short* ob = (z==0 ? Qn : Kn) + ((size_t)b*N_ + nb)*C_;
    #pragma unroll
    for (int ct = 0; ct < 16; ct++){
      int o = 16*ct + lr;
      float bi = bias[o];
      #pragma unroll
      for (int r = 0; r < 4; r++){
        int row = 16*w + 4*lq + r;
        ob[(size_t)row*C_ + o] = f2bf(acc[ct][r] + bi);
      }
    }
  } else {
    #pragma unroll
    for (int ct = 0; ct < 16; ct++){
      int o = 16*ct + lr;
      float bi = bias[o];
      #pragma unroll
      for (int r = 0; r < 4; r++)
        Tlds[16*w + 4*lq + r][o] = f2bf(acc[ct][r] + bi);
    }
    __syncthreads();
    unsigned short* vb = Vc + (size_t)b*C_*N_;
    int j = threadIdx.x & 63, o0 = threadIdx.x >> 6;
    #pragma unroll
    for (int o = o0; o < 256; o += 4)
      vb[(size_t)o*N_ + nb + j] = Tlds[j][o];
  }
}

// ---------------- attention: LDS-staged K/V, no-max softmax, m-split ----------------
// grid (32 nt, 8 b, 2 mh), 256 thr, 72KB LDS -> 2 blocks/CU (8 waves/CU).
// Co-resident blocks are barrier-independent: one computes while the other
// stages. P = exp(S*beta) raw (f32-safe); unnormalized partials -> k_merge.
__global__ __launch_bounds__(256) void k_attn(
    const unsigned short* __restrict__ Qn, const unsigned short* __restrict__ Kn,
    const unsigned short* __restrict__ Vc, const float* __restrict__ beta,
    float* __restrict__ Op, float* __restrict__ Ls)
{
  __shared__ unsigned short Klds[64][256];
  __shared__ unsigned short Vt[256][64];
  __shared__ unsigned short Plds[4][16][64];
  int b = blockIdx.y, nt = blockIdx.x, mh = blockIdx.z;
  int nb = nt*64;
  const unsigned short* Qb = Qn + (size_t)b*N_*C_;
  const unsigned short* Kb = Kn + (size_t)b*N_*C_;
  const unsigned short* Vb = Vc + (size_t)b*C_*N_;
  const float* betab = beta + (size_t)b*N_*N_;
  int w = threadIdx.x >> 6, l = threadIdx.x & 63, lr = l & 15, lq = l >> 4;
  const int mt0 = mh*16;

  // Q fragments (regs, whole kernel)
  s16x8 qf[8];
  {
    const unsigned short* qrow = Qb + (size_t)(nb + 16*w + lr)*C_;
    #pragma unroll
    for (int ks = 0; ks < 8; ks++)
      qf[ks] = *(const s16x8*)&qrow[32*ks + 8*lq];
  }
  f32x4 zero = {0.f,0.f,0.f,0.f};
  f32x4 oacc[16];
  #pragma unroll
  for (int i=0;i<16;i++) oacc[i] = zero;
  float psum[4] = {0.f,0.f,0.f,0.f};

  for (int mt = mt0; mt < mt0+16; mt++){
    int mb = mt*64;
    // stage K [64][256] (swizzled) -- coalesced 16B loads
    for (int i = threadIdx.x; i < 64*32; i += 256){
      int r = i >> 5, cv = i & 31;
      *(s16x8*)&Klds[r][(cv*8) ^ ((r&7)<<3)] = *(const s16x8*)&Kb[(size_t)(mb+r)*C_ + cv*8];
    }
    // stage Vt = V c-major tile [256][64] (swizzled)
    for (int i = threadIdx.x; i < 256*8; i += 256){
      int c = i >> 3, mv = i & 7;
      *(s16x8*)&Vt[c][(mv*8) ^ ((c&7)<<3)] = *(const s16x8*)&Vb[(size_t)c*N_ + mb + mv*8];
    }
    __syncthreads();

    // beta for this tile (issues early, used after QK^T)
    float be[4][4];
    #pragma unroll
    for (int t4=0;t4<4;t4++)
      #pragma unroll
      for (int r=0;r<4;r++)
        be[t4][r] = betab[(size_t)(nb + 16*w + 4*lq + r)*N_ + mb + 16*t4 + lr];

    // S = Q K^T from LDS
    f32x4 s_[4];
    #pragma unroll
    for (int t4=0;t4<4;t4++) s_[t4] = zero;
    #pragma unroll
    for (int ks=0;ks<8;ks++){
      #pragma unroll
      for (int t4=0;t4<4;t4++){
        s16x8 bk_ = *(const s16x8*)&Klds[16*t4 + lr][(32*ks + 8*lq) ^ ((lr&7)<<3)];
        s_[t4] = __builtin_amdgcn_mfma_f32_16x16x32_bf16(qf[ks], bk_, s_[t4], 0, 0, 0);
      }
    }
    // P = exp(S*beta); per-lane row-sums; pack to per-wave Plds
    #pragma unroll
    for (int t4=0;t4<4;t4++)
      #pragma unroll
      for (int r=0;r<4;r++){
        float p_ = __expf(s_[t4][r] * be[t4][r]);
        psum[r] += p_;
        int i_ = 4*lq + r;
        Plds[w][i_][(16*t4 + lr) ^ ((i_&7)<<3)] = f2bf(p_);
      }
    // PV: O += P * V from LDS
    #pragma unroll
    for (int kk=0; kk<2; kk++){
      s16x8 ap_ = *(const s16x8*)&Plds[w][lr][(32*kk + 8*lq) ^ ((lr&7)<<3)];
      #pragma unroll
      for (int ct=0; ct<16; ct++){
        s16x8 bv_ = *(const s16x8*)&Vt[16*ct + lr][(32*kk + 8*lq) ^ ((lr&7)<<3)];
        oacc[ct] = __builtin_amdgcn_mfma_f32_16x16x32_bf16(ap_, bv_, oacc[ct], 0,0,0);
      }
    }
    __syncthreads();
  }

  // reduce row-sums across the 16-lane lr group (lanes share lq -> same rows)
  #pragma unroll
  for (int r=0;r<4;r++){
    #pragma unroll
    for (int d=1; d<16; d<<=1) psum[r] += __shfl_xor(psum[r], d, 64);
  }
  // store partials
  float* Ob = Op + ((size_t)mh*8 + b)*(size_t)N_*C_;
  #pragma unroll
  for (int ct=0; ct<16; ct++)
    #pragma unroll
    for (int r=0;r<4;r++)
      Ob[(size_t)(nb + 16*w + 4*lq + r)*C_ + 16*ct + lr] = oacc[ct][r];
  if (lr == 0){
    float* Lb = Ls + ((size_t)mh*8 + b)*N_;
    #pragma unroll
    for (int r=0;r<4;r++) Lb[nb + 16*w + 4*lq + r] = psum[r];
  }
}

// ---------------- merge the two m-halves, normalize, -> Mn bf16 ----------------
__global__ __launch_bounds__(256) void k_merge(
    const float* __restrict__ Op, const float* __restrict__ Ls,
    unsigned short* __restrict__ Mn)
{
  int gid = blockIdx.x*256 + threadIdx.x;          // 8*2048*64 f32x4 chunks
  int c4 = gid & 63, n = (gid >> 6) & 2047, b = gid >> 17;
  size_t i0 = ((size_t)b*N_ + n)*C_ + c4*4;
  f32x4 o0 = *(const f32x4*)&Op[i0];
  f32x4 o1 = *(const f32x4*)&Op[(size_t)8*N_*C_ + i0];
  float inv = 1.f / (Ls[(size_t)b*N_ + n] + Ls[(size_t)8*N_ + (size_t)b*N_ + n]);
  unsigned short* m = Mn + i0;
  #pragma unroll
  for (int j=0;j<4;j++) m[j] = f2bf((o0[j] + o1[j]) * inv);
}

// ---------------- generic NT GEMM: out[n][o] = epi(sum_c A[n][c] W[o][c]) ----------------
template<int CIN, int COUT, int MODE>
__global__ __launch_bounds__(256) void k_gemm(
    const unsigned short* __restrict__ A, const unsigned short* __restrict__ W,
    const float* __restrict__ bias, const float* __restrict__ sc,
    const float* __restrict__ sh, unsigned short* __restrict__ out)
{
  __shared__ unsigned short Alds[64][CIN];
  int b = blockIdx.y, nt = blockIdx.x, nb = nt*64;
  const unsigned short* Ab = A + ((size_t)b*N_ + nb)*CIN;
  constexpr int PR = CIN/8;
  for (int i = threadIdx.x; i < 64*PR; i += 256){
    int r = i / PR, cv = i % PR;
    *(s16x8*)&Alds[r][(cv*8) ^ ((r&7)<<3)] = *(const s16x8*)&Ab[(size_t)r*CIN + cv*8];
  }
  __syncthreads();
  int w = threadIdx.x >> 6, l = threadIdx.x & 63, lr = l & 15, lq = l >> 4;
  constexpr int NT = COUT/16;
  f32x4 acc[NT];
  f32x4 zero = {0.f,0.f,0.f,0.f};
  #pragma unroll
  for (int i=0;i<NT;i++) acc[i] = zero;
  #pragma unroll
  for (int ks = 0; ks < CIN/32; ks++){
    s16x8 a = *(const s16x8*)&Alds[16*w + lr][(32*ks + 8*lq) ^ ((lr&7)<<3)];
    #pragma unroll
    for (int ct = 0; ct < NT; ct++){
      s16x8 bw = *(const s16x8*)&W[(size_t)(16*ct + lr)*CIN + 32*ks + 8*lq];
      acc[ct] = __builtin_amdgcn_mfma_f32_16x16x32_bf16(a, bw, acc[ct], 0, 0, 0);
    }
  }
  unsigned short* ob = out + ((size_t)b*N_ + nb)*COUT;
  #pragma unroll
  for (int ct = 0; ct < NT; ct++){
    int o = 16*ct + lr;
    float bi = (MODE==0) ? bias[o] : 0.f;
    float s_ = (MODE==1) ? sc[o] : 0.f;
    float h_ = (MODE==1) ? sh[o] : 0.f;
    #pragma unroll
    for (int r = 0; r < 4; r++){
      int row = 16*w + 4*lq + r;
      float y;
      if (MODE==1) y = fmaxf(acc[ct][r]*s_ + h_, 0.f);
      else         y = acc[ct][r] + bi;
      ob[(size_t)row*COUT + o] = f2bf(y);
    }
  }
}

// ---------------- final: out[b][o][n] = x + h2n @ w3^T + b3 ----------------
__global__ __launch_bounds__(256) void k_mlp3(
    const unsigned short* __restrict__ A, const unsigned short* __restrict__ W,
    const float* __restrict__ b3, const float* __restrict__ x,
    float* __restrict__ out)
{
  __shared__ unsigned short Alds[64][128];
  __shared__ float Dlds[64][257];
  int b = blockIdx.y, nt = blockIdx.x, nb = nt*64;
  const unsigned short* Ab = A + ((size_t)b*N_ + nb)*HC;
  for (int i = threadIdx.x; i < 64*16; i += 256){
    int r = i >> 4, cv = i & 15;
    *(s16x8*)&Alds[r][(cv*8) ^ ((r&7)<<3)] = *(const s16x8*)&Ab[(size_t)r*HC + cv*8];
  }
  __syncthreads();
  int w = threadIdx.x >> 6, l = threadIdx.x & 63, lr = l & 15, lq = l >> 4;
  f32x4 acc[16];
  f32x4 zero = {0.f,0.f,0.f,0.f};
  #pragma unroll
  for (int i=0;i<16;i++) acc[i] = zero;
  #pragma unroll
  for (int ks = 0; ks < 4; ks++){
    s16x8 a = *(const s16x8*)&Alds[16*w + lr][(32*ks + 8*lq) ^ ((lr&7)<<3)];
    #pragma unroll
    for (int ct = 0; ct < 16; ct++){
      s16x8 bw = *(const s16x8*)&W[(size_t)(16*ct + lr)*HC + 32*ks + 8*lq];
      acc[ct] = __builtin_amdgcn_mfma_f32_16x16x32_bf16(a, bw, acc[ct], 0, 0, 0);
    }
  }
  #pragma unroll
  for (int ct = 0; ct < 16; ct++){
    int o = 16*ct + lr;
    float bi = b3[o];
    #pragma unroll
    for (int r = 0; r < 4; r++)
      Dlds[16*w + 4*lq + r][o] = acc[ct][r] + bi;
  }
  __syncthreads();
  const float* xb = x + (size_t)b*C_*N_;
  float* ob = out + (size_t)b*C_*N_;
  int j = threadIdx.x & 63, o0 = threadIdx.x >> 6;
  #pragma unroll
  for (int o = o0; o < 256; o += 4)
    ob[(size_t)o*N_ + nb + j] = xb[(size_t)o*N_ + nb + j] + Dlds[j][o];
}

extern "C" void kernel_launch(void* const* d_in, const int* in_sizes, int n_in,
                              void* d_out, int out_size, void* d_ws, size_t ws_size,
                              hipStream_t stream)
{
  const float* x    = (const float*)d_in[0];
  const float* beta = (const float*)d_in[1];
  const float* wq = (const float*)d_in[2];  const float* bq = (const float*)d_in[3];
  const float* wk = (const float*)d_in[4];  const float* bk = (const float*)d_in[5];
  const float* wv = (const float*)d_in[6];  const float* bv = (const float*)d_in[7];
  const float* w1 = (const float*)d_in[8];  const float* b1 = (const float*)d_in[9];
  const float* g1 = (const float*)d_in[10]; const float* be1= (const float*)d_in[11];
  const float* m1 = (const float*)d_in[12]; const float* v1 = (const float*)d_in[13];
  const float* w2 = (const float*)d_in[14]; const float* b2 = (const float*)d_in[15];
  const float* g2 = (const float*)d_in[16]; const float* be2= (const float*)d_in[17];
  const float* m2 = (const float*)d_in[18]; const float* v2 = (const float*)d_in[19];
  const float* w3 = (const float*)d_in[20]; const float* b3 = (const float*)d_in[21];

  char* p = (char*)d_ws;
  auto alloc = [&](size_t n){ char* r = p; p += (n + 255) & ~(size_t)255; return r; };
  unsigned short* xn  = (unsigned short*)alloc((size_t)B_*N_*C_*2);
  unsigned short* Qn  = (unsigned short*)alloc((size_t)B_*N_*C_*2);
  unsigned short* Kn  = (unsigned short*)alloc((size_t)B_*N_*C_*2);
  unsigned short* Vc  = (unsigned short*)alloc((size_t)B_*N_*C_*2);
  unsigned short* Mn  = (unsigned short*)alloc((size_t)B_*N_*C_*2);
  unsigned short* h1n = (unsigned short*)alloc((size_t)B_*N_*HC*2);
  unsigned short* h2n = (unsigned short*)alloc((size_t)B_*N_*HC*2);
  float* Op = (float*)alloc((size_t)2*B_*N_*C_*4);
  float* Ls = (float*)alloc((size_t)2*B_*N_*4);
  unsigned short* wqb = (unsigned short*)alloc(65536*2);
  unsigned short* wkb = (unsigned short*)alloc(65536*2);
  unsigned short* wvb = (unsigned short*)alloc(65536*2);
  unsigned short* w1b = (unsigned short*)alloc(32768*2);
  unsigned short* w2b = (unsigned short*)alloc(16384*2);
  unsigned short* w3b = (unsigned short*)alloc(32768*2);
  float* sc1 = (float*)alloc(128*4);
  float* sh1 = (float*)alloc(128*4);
  float* sc2 = (float*)alloc(128*4);
  float* sh2 = (float*)alloc(128*4);

  PrepArgs pa;
  pa.s0 = wq; pa.s1 = wk; pa.s2 = wv; pa.s3 = w1; pa.s4 = w2; pa.s5 = w3;
  pa.d0 = wqb; pa.d1 = wkb; pa.d2 = wvb; pa.d3 = w1b; pa.d4 = w2b; pa.d5 = w3b;
  pa.b1 = b1; pa.g1 = g1; pa.be1 = be1; pa.m1 = m1; pa.v1 = v1;
  pa.b2 = b2; pa.g2 = g2; pa.be2 = be2; pa.m2 = m2; pa.v2 = v2;
  pa.sc1 = sc1; pa.sh1 = sh1; pa.sc2 = sc2; pa.sh2 = sh2;

  k_prep<<<dim3(1089), dim3(256), 0, stream>>>(pa);
  k_transpose_x<<<dim3(32, 4, 8), dim3(256), 0, stream>>>(x, xn);
  k_qkv<<<dim3(32, 8, 3), dim3(256), 0, stream>>>(xn, wqb, wkb, wvb, bq, bk, bv, Qn, Kn, Vc);
  k_attn<<<dim3(32, 8, 2), dim3(256), 0, stream>>>(Qn, Kn, Vc, beta, Op, Ls);
  k_merge<<<dim3(4096), dim3(256), 0, stream>>>(Op, Ls, Mn);
  k_gemm<256,128,1><<<dim3(32, 8), dim3(256), 0, stream>>>(Mn, w1b, b1, sc1, sh1, h1n);
  k_gemm<128,128,1><<<dim3(32, 8), dim3(256), 0, stream>>>(h1n, w2b, b2, sc2, sh2, h2n);
  k_mlp3<<<dim3(32, 8), dim3(256), 0, stream>>>(h2n, w3b, b3, x, (float*)d_out);
}